// Round 10
// baseline (706.258 us; speedup 1.0000x reference)
//
#include <hip/hip_runtime.h>
#include <math.h>

typedef _Float16 f16;
typedef _Float16 f16x2 __attribute__((ext_vector_type(2)));
typedef _Float16 f16x4 __attribute__((ext_vector_type(4)));
typedef _Float16 f16x8 __attribute__((ext_vector_type(8)));
typedef float f32x4 __attribute__((ext_vector_type(4)));

#define NN 5000
#define NE 160000

// ---------------- ws layout (bytes, all 16B-aligned) ----------------
#define OFF_W2T   0ul          // f16 [21][256][4][8] fragment-linear (344064 B)
#define OFF_W3T   344064ul     // f16 [1248]
#define OFF_WT1   346560ul     // f16 [512][96]
#define OFF_WT2   444864ul     // f16 [512][128]
#define OFF_WT3   575936ul
#define OFF_WT4   707008ul
#define OFF_WT5   838080ul
#define OFF_WT6   969152ul     // f16 [64][128]
#define OFF_H0    985536ul     // f16 [5000][96]
#define OFF_HA    1945536ul    // f16 [5000][128]
#define OFF_HB    3225536ul    // f16 [5000][128]
#define OFF_C     4505536ul    // f32 [5000][256] root (also f32 [5000][64] layer 6)
#define OFF_CT    9625536ul    // f16 [5000][256] t-part (gathered)
#define OFF_DEG   14745536ul   // int [5000]
#define OFF_IP    14765536ul   // int [5001]
#define OFF_CUR   14785568ul   // int [5000]
#define OFF_DINV  14805568ul   // f32 [5000]
#define OFF_CSRS  14825568ul   // int [160000]
#define OFF_CSRN  15465568ul   // f32 [160000]
// W1T f16 [112][32] aliases OFF_C (dead before first gemm writes CR)
#define OFF_W1T   OFF_C

// ---------------- CNN LDS layout (dynamic, 74496 B) ----------------
#define L_IN   0
#define L_BUF  1280
#define L_A1   (L_BUF)
#define L_C1   (L_BUF + 16640)            // 17920
#define L_C2   (L_BUF)
#define C1_STRIDE 136                     // f16 elems (272 B/row)
#define LDS_TOTAL (17920 + 208*272)       // 74496; x2 = 148992 <= 160 KiB -> 2 blocks/CU

// ==================== fused weight-prep ====================
__device__ __forceinline__ void wt_body(int i, const float* wi, const float* wr,
                                        f16* WT, int Kst, int Fin, int Fout, int Kpad) {
  int n = i / Kpad, kk = i - n*Kpad;
  float v = 0.f;
  if (kk < Fin) {
    int path = n / (Kst*Fout);
    if (path < 2) {
      int rem = n - path*(Kst*Fout);
      int k = rem / Fout, fo = rem - k*Fout;
      const float* w = (path == 0) ? wi : wr;
      v = w[(k*Fin + kk)*Fout + fo];
    }
  }
  WT[i] = (f16)v;
}

// grid: [0,672) W2T | [672,677) W3T | [677,691) W1T | [691,883) WT1 |
// [883,1139) WT2 | [1139,1395) WT3 | [1395,1651) WT4 | [1651,1907) WT5 | [1907,1939) WT6
__global__ void prep_all(char* ws, const float* __restrict__ e1w,
                         const float* __restrict__ e2w, const float* __restrict__ e3w,
                         const float* wi1, const float* wr1, const float* wi2, const float* wr2,
                         const float* wi3, const float* wr3, const float* wi4, const float* wr4,
                         const float* wi5, const float* wr5, const float* wi6, const float* wr6) {
  int b = blockIdx.x, tid = threadIdx.x;
  if (b < 672) {                                  // W2T fragment-linear
    int i = b*256 + tid;
    int kc = i >> 13, n = (i >> 5) & 255;
    int k = i & 31;                               // k offset within kc (= g*8+j)
    int kk = kc*32 + k;
    int tap = kk / 112, c = kk - tap*112;
    float v = 0.f;
    if (n < 200 && c < 100 && tap < 6) v = e2w[n*600 + c*6 + tap];
    ((f16*)(ws + OFF_W2T))[i] = (f16)v;
  } else if (b < 677) {                           // W3T
    int i = (b - 672)*256 + tid;
    if (i < 1248) {
      int tap = i / 208, c = i - tap*208;
      float v = (c < 200) ? e3w[c*6 + tap] : 0.f;
      ((f16*)(ws + OFF_W3T))[i] = (f16)v;
    }
  } else if (b < 691) {                           // W1T
    int i = (b - 677)*256 + tid;
    if (i < 112*32) {
      int n = i >> 5, k = i & 31;
      float v = (n < 100 && k < 9) ? e1w[n*9 + k] : 0.f;
      ((f16*)(ws + OFF_W1T))[i] = (f16)v;
    }
  } else if (b < 883) {
    wt_body((b - 691)*256 + tid, wi1, wr1, (f16*)(ws + OFF_WT1), 2, 94, 128, 96);
  } else if (b < 1139) {
    wt_body((b - 883)*256 + tid, wi2, wr2, (f16*)(ws + OFF_WT2), 2, 128, 128, 128);
  } else if (b < 1395) {
    wt_body((b - 1139)*256 + tid, wi3, wr3, (f16*)(ws + OFF_WT3), 2, 128, 128, 128);
  } else if (b < 1651) {
    wt_body((b - 1395)*256 + tid, wi4, wr4, (f16*)(ws + OFF_WT4), 2, 128, 128, 128);
  } else if (b < 1907) {
    wt_body((b - 1651)*256 + tid, wi5, wr5, (f16*)(ws + OFF_WT5), 2, 128, 128, 128);
  } else {
    wt_body((b - 1907)*256 + tid, wi6, wr6, (f16*)(ws + OFF_WT6), 1, 128, 16, 128);
  }
}

// ==================== graph kernels ====================
__global__ void deg_kernel(const int* __restrict__ ei, int* __restrict__ deg) {
  int e = blockIdx.x*256 + threadIdx.x;
  if (e < NE) atomicAdd(&deg[ei[NE + e]], 1);
}

__global__ __launch_bounds__(1024) void scan_kernel(const int* __restrict__ deg,
                                                    int* __restrict__ ip,
                                                    float* __restrict__ dinv) {
  __shared__ int buf[1024];
  __shared__ int s_carry;
  const int tid = threadIdx.x;
  if (tid == 0) s_carry = 0;
  __syncthreads();
  for (int base = 0; base < NN; base += 1024) {
    int i = base + tid;
    int v = (i < NN) ? deg[i] : 0;
    buf[tid] = v;
    __syncthreads();
    for (int off = 1; off < 1024; off <<= 1) {
      int t = (tid >= off) ? buf[tid - off] : 0;
      __syncthreads();
      buf[tid] += t;
      __syncthreads();
    }
    int incl = buf[tid];
    int c = s_carry;
    if (i < NN) {
      ip[i] = c + incl - v;
      dinv[i] = (v > 0) ? rsqrtf((float)v) : 0.f;
    }
    __syncthreads();
    if (tid == 1023) s_carry = c + buf[1023];
    __syncthreads();
  }
  if (tid == 0) ip[NN] = s_carry;
}

__global__ void csr_fill(const int* __restrict__ ei, const float* __restrict__ dinv,
                         const int* __restrict__ ip, int* __restrict__ cur,
                         int* __restrict__ csrs, float* __restrict__ csrn) {
  int e = blockIdx.x*256 + threadIdx.x;
  if (e >= NE) return;
  int s = ei[e], d = ei[NE + e];
  int pos = ip[d] + atomicAdd(&cur[d], 1);
  csrs[pos] = s;
  csrn[pos] = dinv[s]*dinv[d];
}

// ==================== fused CNN encoder ====================
// 512 threads (8 waves), conv2 wave grid 2M x 4N, acc[5][4]=80 AGPR.
// Arch regs measured 48 at acc[5][2] (r9) -> 48+80 = 128 exact (512,4) fit.
// 2 blocks/CU (LDS 149KB) -> cross-block phase overlap; LDS A-reads halved.
__global__ __launch_bounds__(512, 4) void cnn_kernel(
    const float* __restrict__ inp, const f16* __restrict__ W1T, const float* __restrict__ b1,
    const f16* __restrict__ W2T, const float* __restrict__ b2,
    const f16* __restrict__ W3T, const float* __restrict__ b3,
    f16* __restrict__ h0)
{
  extern __shared__ char smem[];
  float* s_in = (float*)(smem + L_IN);    // [53][6] f32
  f16*   s_a1 = (f16*)(smem + L_A1);      // [208][40] im2col (k<9 data)
  f16*   s_c1 = (f16*)(smem + L_C1);      // [208][136] row'=y+52x, col=cin
  f16*   s_c2 = (f16*)(smem + L_C2);      // [147][216] row=3*y3+x3, col=cout

  const int node = blockIdx.x;
  const int tid  = threadIdx.x;
  const int lane = tid & 63, wid = tid >> 6;     // wid 0..7
  const int l15 = lane & 15, g = lane >> 4;

  for (int i = tid; i < 318; i += 512) s_in[i] = inp[node*318 + i];
  __syncthreads();

  // ---- im2col A1[m][k] = in[(y+ky)*6 + x+kx], m=4y+x, k=ky*3+kx ----
  for (int i = tid; i < 208*32; i += 512) {
    int m = i >> 5, k = i & 31;
    float v = 0.f;
    if (m < 204 && k < 9) {
      int y = m >> 2, x = m & 3;
      int ky = (k >= 6) ? 2 : (k >= 3 ? 1 : 0);
      int kx = k - ky*3;
      v = s_in[(y + ky)*6 + x + kx];
    }
    s_a1[m*40 + k] = (f16)v;
  }
  __syncthreads();

  // ---- conv1 (1->100) SWAPPED MFMA: D[cout][pos]; covers ALL 208x112 of c1 ----
  for (int p = wid; p < 91; p += 8) {
    int mt = p % 13, nt = p / 13;
    f16x8 a = *(const f16x8*)(W1T + (nt*16 + l15)*32 + g*8);   // A row = cout
    f16x8 b = *(const f16x8*)(s_a1 + (mt*16 + l15)*40 + g*8);  // B col = position
    f32x4 acc = (f32x4){0.f,0.f,0.f,0.f};
    acc = __builtin_amdgcn_mfma_f32_16x16x32_f16(a, b, acc, 0, 0, 0);
    int m = mt*16 + l15;                         // position m = 4y+x
    int rowp = (m >> 2) + 52*(m & 3);            // column-major row'
    int cb = nt*16 + g*4;
    f16x4 pack;
    #pragma unroll
    for (int j = 0; j < 4; j++) {
      int c = cb + j;
      float bias = (c < 100) ? b1[c] : 0.f;      // cout>=100: W1T rows zero -> acc 0
      float v = acc[j] + bias;
      v = v > 0.f ? v : 0.01f*v;
      pack[j] = (f16)v;
    }
    *(f16x4*)(s_c1 + rowp*C1_STRIDE + cb) = pack;
  }
  __syncthreads();

  // ---- conv2 (100->200) SWAPPED MFMA GEMM: D[cout][pos], wave tile 80M x 64N ----
  const int wm = wid >> 2, wn = wid & 3;          // 2x4 wave grid

  const f16* abase[5];
  #pragma unroll
  for (int mi = 0; mi < 5; mi++) {
    int p = (wm*5 + mi)*16 + l15;
    int pp = p < 147 ? p : 0;
    int y2 = pp / 3;
    int x2 = pp - y2*3;
    abase[mi] = s_c1 + (y2 + 52*x2)*C1_STRIDE + g*8;
  }

  f32x4 acc[5][4];
  #pragma unroll
  for (int mi = 0; mi < 5; mi++)
    #pragma unroll
    for (int ni = 0; ni < 4; ni++)
      acc[mi][ni] = (f32x4){0.f,0.f,0.f,0.f};

  const f16* bbase = W2T + wn*2048 + l15*32 + g*8;   // fragment-linear, lane row = cout
  #pragma unroll
  for (int kc = 0; kc < 21; kc++) {
    f16x8 b[4];
    const f16* bkc = bbase + kc*8192;
    #pragma unroll
    for (int ni = 0; ni < 4; ni++)
      b[ni] = *(const f16x8*)(bkc + ni*512);
    int kg0 = kc*32;
    int tap0 = kg0 / 112;
    int rem0 = kg0 - tap0*112;
    int cfull = rem0 + g*8;
    int wrap = cfull >= 112 ? 1 : 0;
    int c = cfull - wrap*112;
    int tapg = tap0 + wrap;                       // tap = ky*2+kx
    int dr = (tapg >> 1) + 52*(tapg & 1);         // row' delta = ky + 52*kx
    int aoff = dr*C1_STRIDE + (c - g*8);          // abase already has +g*8
    #pragma unroll
    for (int mi = 0; mi < 5; mi++) {
      f16x8 a = *(const f16x8*)(abase[mi] + aoff);
      #pragma unroll
      for (int ni = 0; ni < 4; ni++)   // SWAPPED: A-op = weights, B-op = activations
        acc[mi][ni] = __builtin_amdgcn_mfma_f32_16x16x32_f16(b[ni], a, acc[mi][ni], 0, 0, 0);
    }
  }

  __syncthreads();   // all reads of s_c1/s_a1 done before s_c2 overwrites

  // epilogue: D[row=cout][col=pos]; packed b64 stores. GUARD nb<216 (race fix, r6).
  #pragma unroll
  for (int ni = 0; ni < 4; ni++) {
    int nb = wn*64 + ni*16 + g*4;
    if (nb < 216) {
      #pragma unroll
      for (int mi = 0; mi < 5; mi++) {
        int m = (wm*5 + mi)*16 + l15;
        if (m < 147) {
          f16x4 pack;
          #pragma unroll
          for (int j = 0; j < 4; j++) {
            int n = nb + j;
            float bias = (n < 200) ? b2[n] : 0.f;
            float v = acc[mi][ni][j] + bias;
            v = v > 0.f ? v : 0.01f*v;
            pack[j] = (f16)v;
          }
          *(f16x4*)(s_c2 + m*216 + nb) = pack;
        }
      }
    }
  }
  __syncthreads();

  // ---- conv3 (200->1) SWAPPED skinny MFMA + tanh -> h0 ----
  if (wid < 6) {
    int pos = wid*16 + l15;
    int q = pos < 94 ? pos : 0;
    int r3 = (q >> 1)*3 + (q & 1);
    f32x4 acc3 = (f32x4){0.f,0.f,0.f,0.f};
    #pragma unroll
    for (int kc = 0; kc < 39; kc++) {
      int k = kc*32 + g*8;
      int tap = k / 208;
      int c = k - tap*208;
      int dr = (tap >> 1)*3 + (tap & 1);
      f16x8 a = *(const f16x8*)(W3T + k);
      f16x8 b = *(const f16x8*)(s_c2 + (r3 + dr)*216 + c);
      acc3 = __builtin_amdgcn_mfma_f32_16x16x32_f16(a, b, acc3, 0, 0, 0);
    }
    if (g == 0) {
      float v = (pos < 94) ? tanhf(acc3[0] + b3[0]) : 0.f;
      h0[node*96 + pos] = (f16)v;
    }
  }
}

// ==================== generic MFMA GEMM: out = A[M][K] * B[N][K]^T ====================
// CT != null: cols 0..255 -> CT f16 [M][256] (t-part); cols 256..511 -> Croot f32 [M][256]
// CT == null: all cols -> Croot f32 [M][N]
template<int K>
__global__ __launch_bounds__(256, 4) void gemm_kernel(
    const f16* __restrict__ A, const f16* __restrict__ B, float* __restrict__ Croot,
    f16* __restrict__ CT, int M, int N)
{
  constexpr int LK = K + 8;
  __shared__ f16 sA[64*LK];
  __shared__ f16 sB[64*LK];
  const int tid = threadIdx.x;
  const int m0 = blockIdx.x*64, n0 = blockIdx.y*64;
  constexpr int SEGS = K/8;
  for (int i = tid; i < 64*SEGS; i += 256) {
    int row = i / SEGS, seg = i - row*SEGS;
    int gm = m0 + row; if (gm >= M) gm = M - 1;
    *(f16x8*)(sA + row*LK + seg*8) = *(const f16x8*)(A + (size_t)gm*K + seg*8);
    *(f16x8*)(sB + row*LK + seg*8) = *(const f16x8*)(B + (size_t)(n0 + row)*K + seg*8);
  }
  __syncthreads();
  const int lane = tid & 63, wid = tid >> 6;
  const int l15 = lane & 15, g = lane >> 4;
  const int wm = wid >> 1, wn = wid & 1;
  f32x4 acc[2][2];
  #pragma unroll
  for (int mi = 0; mi < 2; mi++)
    #pragma unroll
    for (int ni = 0; ni < 2; ni++)
      acc[mi][ni] = (f32x4){0.f,0.f,0.f,0.f};
  #pragma unroll
  for (int kc = 0; kc < K/32; kc++) {
    f16x8 a[2], b[2];
    #pragma unroll
    for (int mi = 0; mi < 2; mi++)
      a[mi] = *(const f16x8*)(sA + (wm*32 + mi*16 + l15)*LK + kc*32 + g*8);
    #pragma unroll
    for (int ni = 0; ni < 2; ni++)
      b[ni] = *(const f16x8*)(sB + (wn*32 + ni*16 + l15)*LK + kc*32 + g*8);
    #pragma unroll
    for (int mi = 0; mi < 2; mi++)
      #pragma unroll
      for (int ni = 0; ni < 2; ni++)
        acc[mi][ni] = __builtin_amdgcn_mfma_f32_16x16x32_f16(a[mi], b[ni], acc[mi][ni], 0, 0, 0);
  }
  if (CT != nullptr && n0 < 256) {
    #pragma unroll
    for (int mi = 0; mi < 2; mi++)
      #pragma unroll
      for (int ni = 0; ni < 2; ni++)
        #pragma unroll
        for (int j = 0; j < 4; j++) {
          int m = m0 + wm*32 + mi*16 + g*4 + j;
          int n = n0 + wn*32 + ni*16 + l15;
          if (m < M) CT[(size_t)m*256 + n] = (f16)acc[mi][ni][j];
        }
  } else if (CT != nullptr) {
    #pragma unroll
    for (int mi = 0; mi < 2; mi++)
      #pragma unroll
      for (int ni = 0; ni < 2; ni++)
        #pragma unroll
        for (int j = 0; j < 4; j++) {
          int m = m0 + wm*32 + mi*16 + g*4 + j;
          int n = n0 + wn*32 + ni*16 + l15 - 256;
          if (m < M) Croot[(size_t)m*256 + n] = acc[mi][ni][j];
        }
  } else {
    #pragma unroll
    for (int mi = 0; mi < 2; mi++)
      #pragma unroll
      for (int ni = 0; ni < 2; ni++)
        #pragma unroll
        for (int j = 0; j < 4; j++) {
          int m = m0 + wm*32 + mi*16 + g*4 + j;
          int n = n0 + wn*32 + ni*16 + l15;
          if (m < M) Croot[(size_t)m*N + n] = acc[mi][ni][j];
        }
  }
}

// ==================== ARMA combine kernels ====================
// CT row: [t_k0(128)|t_k1(128)] f16; Croot row: [root_k0(128)|root_k1(128)] f32
// lane owns cols {2l, 2l+1}
__global__ __launch_bounds__(256) void combine128(
    const f16* __restrict__ CT, const float* __restrict__ Croot,
    const int* __restrict__ ip, const int* __restrict__ csrs,
    const float* __restrict__ csrn, const float* __restrict__ bias,
    f16* __restrict__ hout)
{
  const int d = blockIdx.x*4 + (threadIdx.x >> 6);
  const int lane = threadIdx.x & 63;
  const int c = lane*2;
  const int i0 = ip[d], i1 = ip[d+1];
  float a00=0.f, a01=0.f, a10=0.f, a11=0.f;
  float b00=0.f, b01=0.f, b10=0.f, b11=0.f;
  int e = i0;
  for (; e + 1 < i1; e += 2) {                   // 2-edge unroll, 8 streams
    int s0 = csrs[e], s1 = csrs[e+1];
    float w0 = csrn[e], w1 = csrn[e+1];
    f16x2 t00 = *(const f16x2*)(CT + (size_t)s0*256 + c);
    f16x2 t01 = *(const f16x2*)(CT + (size_t)s0*256 + 128 + c);
    f16x2 t10 = *(const f16x2*)(CT + (size_t)s1*256 + c);
    f16x2 t11 = *(const f16x2*)(CT + (size_t)s1*256 + 128 + c);
    a00 += w0*(float)t00.x;  a01 += w0*(float)t00.y;
    a10 += w0*(float)t01.x;  a11 += w0*(float)t01.y;
    b00 += w1*(float)t10.x;  b01 += w1*(float)t10.y;
    b10 += w1*(float)t11.x;  b11 += w1*(float)t11.y;
  }
  if (e < i1) {
    int s = csrs[e];
    float w = csrn[e];
    f16x2 t0 = *(const f16x2*)(CT + (size_t)s*256 + c);
    f16x2 t1 = *(const f16x2*)(CT + (size_t)s*256 + 128 + c);
    a00 += w*(float)t0.x;  a01 += w*(float)t0.y;
    a10 += w*(float)t1.x;  a11 += w*(float)t1.y;
  }
  a00 += b00; a01 += b01; a10 += b10; a11 += b11;
  const float* r = Croot + (size_t)d*256;
  float o0 = 0.5f*(fmaxf(a00 + r[c]       + bias[c],       0.f)
                 + fmaxf(a10 + r[128 + c] + bias[128 + c], 0.f));
  float o1 = 0.5f*(fmaxf(a01 + r[c + 1]   + bias[c + 1],   0.f)
                 + fmaxf(a11 + r[129 + c] + bias[129 + c], 0.f));
  f16x2 ov; ov.x = (f16)tanhf(o0); ov.y = (f16)tanhf(o1);
  *(f16x2*)(hout + (size_t)d*128 + c) = ov;
}

// layer 6 (K=1, Fout=16): CR row = [t(16)|root(16)|...]; relu -> softmax -> out
__global__ __launch_bounds__(256) void combine_out(
    const float* __restrict__ C, const int* __restrict__ ip,
    const int* __restrict__ csrs, const float* __restrict__ csrn,
    const float* __restrict__ bias, float* __restrict__ out)
{
  const int d = blockIdx.x*4 + (threadIdx.x >> 6);
  const int lane = threadIdx.x & 63;
  const int f = lane & 15;
  const int i0 = ip[d], i1 = ip[d+1];
  float a = 0.f, b = 0.f;
  int e = i0;
  for (; e + 1 < i1; e += 2) {
    a += csrn[e]   * C[(size_t)csrs[e]*64 + f];
    b += csrn[e+1] * C[(size_t)csrs[e+1]*64 + f];
  }
  if (e < i1) a += csrn[e] * C[(size_t)csrs[e]*64 + f];
  a += b;
  float v = fmaxf(a + C[(size_t)d*64 + 16 + f] + bias[f], 0.f);
  float m = v;
  #pragma unroll
  for (int off = 1; off < 16; off <<= 1) m = fmaxf(m, __shfl_xor(m, off));
  float ev = expf(v - m);
  float s = ev;
  #pragma unroll
  for (int off = 1; off < 16; off <<= 1) s += __shfl_xor(s, off);
  if (lane < 16) out[(size_t)d*16 + lane] = ev / s;
}

// ==================== host ====================
extern "C" void kernel_launch(void* const* d_in, const int* in_sizes, int n_in,
                              void* d_out, int out_size, void* d_ws, size_t ws_size,
                              hipStream_t stream)
{
  const float* inputs = (const float*)d_in[0];
  const int*   ei     = (const int*)d_in[1];
  const float* e1w = (const float*)d_in[2];
  const float* e1b = (const float*)d_in[3];
  const float* e2w = (const float*)d_in[4];
  const float* e2b = (const float*)d_in[5];
  const float* e3w = (const float*)d_in[6];
  const float* e3b = (const float*)d_in[7];
  const float *awi[6], *awr[6], *ab[6];
  for (int i = 0; i < 6; i++) {
    awi[i] = (const float*)d_in[8 + 3*i];
    awr[i] = (const float*)d_in[9 + 3*i];
    ab[i]  = (const float*)d_in[10 + 3*i];
  }
  char* ws = (char*)d_ws;
  f16* W2T = (f16*)(ws + OFF_W2T);
  f16* W3T = (f16*)(ws + OFF_W3T);
  f16* W1T = (f16*)(ws + OFF_W1T);
  f16* WT[6] = { (f16*)(ws + OFF_WT1), (f16*)(ws + OFF_WT2), (f16*)(ws + OFF_WT3),
                 (f16*)(ws + OFF_WT4), (f16*)(ws + OFF_WT5), (f16*)(ws + OFF_WT6) };
  f16* H0 = (f16*)(ws + OFF_H0);
  f16* HA = (f16*)(ws + OFF_HA);
  f16* HB = (f16*)(ws + OFF_HB);
  float* CR = (float*)(ws + OFF_C);
  f16* CT  = (f16*)(ws + OFF_CT);
  int* DEG = (int*)(ws + OFF_DEG);
  int* IP  = (int*)(ws + OFF_IP);
  int* CUR = (int*)(ws + OFF_CUR);
  float* DINV = (float*)(ws + OFF_DINV);
  int* CSRS = (int*)(ws + OFF_CSRS);
  float* CSRN = (float*)(ws + OFF_CSRN);

  (void)hipFuncSetAttribute((const void*)cnn_kernel,
                            hipFuncAttributeMaxDynamicSharedMemorySize, LDS_TOTAL);

  // all weight prep in ONE launch (W1T aliases CR; cnn reads it before gemm writes CR)
  prep_all<<<1939, 256, 0, stream>>>(ws, e1w, e2w, e3w,
                                     awi[0], awr[0], awi[1], awr[1], awi[2], awr[2],
                                     awi[3], awr[3], awi[4], awr[4], awi[5], awr[5]);

  // graph norm + CSR by dst
  (void)hipMemsetAsync(DEG, 0, NN*sizeof(int), stream);
  (void)hipMemsetAsync(CUR, 0, NN*sizeof(int), stream);
  deg_kernel<<<625, 256, 0, stream>>>(ei, DEG);
  scan_kernel<<<1, 1024, 0, stream>>>(DEG, IP, DINV);
  csr_fill<<<625, 256, 0, stream>>>(ei, DINV, IP, CUR, CSRS, CSRN);

  // fused CNN encoder -> h0 f16 [5000][96]
  cnn_kernel<<<NN, 512, LDS_TOTAL, stream>>>(inputs, W1T, e1b, W2T, e2b, W3T, e3b, H0);

  // ARMA stack
  gemm_kernel<96><<<dim3(79, 8), 256, 0, stream>>>(H0, WT[0], CR, CT, NN, 512);
  combine128<<<1250, 256, 0, stream>>>(CT, CR, IP, CSRS, CSRN, ab[0], HA);
  gemm_kernel<128><<<dim3(79, 8), 256, 0, stream>>>(HA, WT[1], CR, CT, NN, 512);
  combine128<<<1250, 256, 0, stream>>>(CT, CR, IP, CSRS, CSRN, ab[1], HB);
  gemm_kernel<128><<<dim3(79, 8), 256, 0, stream>>>(HB, WT[2], CR, CT, NN, 512);
  combine128<<<1250, 256, 0, stream>>>(CT, CR, IP, CSRS, CSRN, ab[2], HA);
  gemm_kernel<128><<<dim3(79, 8), 256, 0, stream>>>(HA, WT[3], CR, CT, NN, 512);
  combine128<<<1250, 256, 0, stream>>>(CT, CR, IP, CSRS, CSRN, ab[3], HB);
  gemm_kernel<128><<<dim3(79, 8), 256, 0, stream>>>(HB, WT[4], CR, CT, NN, 512);
  combine128<<<1250, 256, 0, stream>>>(CT, CR, IP, CSRS, CSRN, ab[4], HA);
  gemm_kernel<128><<<dim3(79, 1), 256, 0, stream>>>(HA, WT[5], CR, nullptr, NN, 64);
  combine_out<<<1250, 256, 0, stream>>>(CR, IP, CSRS, CSRN, ab[5], (float*)d_out);
}

// Round 11
// 654.231 us; speedup vs baseline: 1.0795x; 1.0795x over previous
//
#include <hip/hip_runtime.h>
#include <math.h>

typedef _Float16 f16;
typedef _Float16 f16x2 __attribute__((ext_vector_type(2)));
typedef _Float16 f16x4 __attribute__((ext_vector_type(4)));
typedef _Float16 f16x8 __attribute__((ext_vector_type(8)));
typedef float f32x4 __attribute__((ext_vector_type(4)));

#define NN 5000
#define NE 160000

// ---------------- ws layout (bytes, all 16B-aligned) ----------------
#define OFF_W2T   0ul          // f16 [21][256][4][8] fragment-linear (344064 B)
#define OFF_W3T   344064ul     // f16 [1248]
#define OFF_WT1   346560ul     // f16 [512][96]
#define OFF_WT2   444864ul     // f16 [512][128]
#define OFF_WT3   575936ul
#define OFF_WT4   707008ul
#define OFF_WT5   838080ul
#define OFF_WT6   969152ul     // f16 [64][128]
#define OFF_H0    985536ul     // f16 [5000][96]
#define OFF_HA    1945536ul    // f16 [5000][128]
#define OFF_HB    3225536ul    // f16 [5000][128]
#define OFF_C     4505536ul    // f32 [5000][256] root (also f32 [5000][64] layer 6)
#define OFF_CT    9625536ul    // f16 [5000][256] t-part (gathered)
#define OFF_DEG   14745536ul   // int [5000]
#define OFF_IP    14765536ul   // int [5001]
#define OFF_CUR   14785568ul   // int [5000]
#define OFF_DINV  14805568ul   // f32 [5000]
#define OFF_CSRS  14825568ul   // int [160000]
#define OFF_CSRN  15465568ul   // f32 [160000]
// W1T f16 [112][32] aliases OFF_C (dead before first gemm writes CR)
#define OFF_W1T   OFF_C

// ---------------- CNN LDS layout (dynamic, 74496 B) ----------------
#define L_IN   0
#define L_BUF  1280
#define L_A1   (L_BUF)
#define L_C1   (L_BUF + 16640)            // 17920
#define L_C2   (L_BUF)
#define C1_STRIDE 136                     // f16 elems (272 B/row)
#define LDS_TOTAL (17920 + 208*272)       // 74496

// ==================== fused weight-prep ====================
__device__ __forceinline__ void wt_body(int i, const float* wi, const float* wr,
                                        f16* WT, int Kst, int Fin, int Fout, int Kpad) {
  int n = i / Kpad, kk = i - n*Kpad;
  float v = 0.f;
  if (kk < Fin) {
    int path = n / (Kst*Fout);
    if (path < 2) {
      int rem = n - path*(Kst*Fout);
      int k = rem / Fout, fo = rem - k*Fout;
      const float* w = (path == 0) ? wi : wr;
      v = w[(k*Fin + kk)*Fout + fo];
    }
  }
  WT[i] = (f16)v;
}

// grid: [0,672) W2T | [672,677) W3T | [677,691) W1T | [691,883) WT1 |
// [883,1139) WT2 | [1139,1395) WT3 | [1395,1651) WT4 | [1651,1907) WT5 | [1907,1939) WT6
__global__ void prep_all(char* ws, const float* __restrict__ e1w,
                         const float* __restrict__ e2w, const float* __restrict__ e3w,
                         const float* wi1, const float* wr1, const float* wi2, const float* wr2,
                         const float* wi3, const float* wr3, const float* wi4, const float* wr4,
                         const float* wi5, const float* wr5, const float* wi6, const float* wr6) {
  int b = blockIdx.x, tid = threadIdx.x;
  if (b < 672) {                                  // W2T fragment-linear
    int i = b*256 + tid;
    int kc = i >> 13, n = (i >> 5) & 255;
    int k = i & 31;                               // k offset within kc (= g*8+j)
    int kk = kc*32 + k;
    int tap = kk / 112, c = kk - tap*112;
    float v = 0.f;
    if (n < 200 && c < 100 && tap < 6) v = e2w[n*600 + c*6 + tap];
    ((f16*)(ws + OFF_W2T))[i] = (f16)v;
  } else if (b < 677) {                           // W3T
    int i = (b - 672)*256 + tid;
    if (i < 1248) {
      int tap = i / 208, c = i - tap*208;
      float v = (c < 200) ? e3w[c*6 + tap] : 0.f;
      ((f16*)(ws + OFF_W3T))[i] = (f16)v;
    }
  } else if (b < 691) {                           // W1T
    int i = (b - 677)*256 + tid;
    if (i < 112*32) {
      int n = i >> 5, k = i & 31;
      float v = (n < 100 && k < 9) ? e1w[n*9 + k] : 0.f;
      ((f16*)(ws + OFF_W1T))[i] = (f16)v;
    }
  } else if (b < 883) {
    wt_body((b - 691)*256 + tid, wi1, wr1, (f16*)(ws + OFF_WT1), 2, 94, 128, 96);
  } else if (b < 1139) {
    wt_body((b - 883)*256 + tid, wi2, wr2, (f16*)(ws + OFF_WT2), 2, 128, 128, 128);
  } else if (b < 1395) {
    wt_body((b - 1139)*256 + tid, wi3, wr3, (f16*)(ws + OFF_WT3), 2, 128, 128, 128);
  } else if (b < 1651) {
    wt_body((b - 1395)*256 + tid, wi4, wr4, (f16*)(ws + OFF_WT4), 2, 128, 128, 128);
  } else if (b < 1907) {
    wt_body((b - 1651)*256 + tid, wi5, wr5, (f16*)(ws + OFF_WT5), 2, 128, 128, 128);
  } else {
    wt_body((b - 1907)*256 + tid, wi6, wr6, (f16*)(ws + OFF_WT6), 1, 128, 16, 128);
  }
}

// ==================== graph kernels ====================
__global__ void deg_kernel(const int* __restrict__ ei, int* __restrict__ deg) {
  int e = blockIdx.x*256 + threadIdx.x;
  if (e < NE) atomicAdd(&deg[ei[NE + e]], 1);
}

__global__ __launch_bounds__(1024) void scan_kernel(const int* __restrict__ deg,
                                                    int* __restrict__ ip,
                                                    float* __restrict__ dinv) {
  __shared__ int buf[1024];
  __shared__ int s_carry;
  const int tid = threadIdx.x;
  if (tid == 0) s_carry = 0;
  __syncthreads();
  for (int base = 0; base < NN; base += 1024) {
    int i = base + tid;
    int v = (i < NN) ? deg[i] : 0;
    buf[tid] = v;
    __syncthreads();
    for (int off = 1; off < 1024; off <<= 1) {
      int t = (tid >= off) ? buf[tid - off] : 0;
      __syncthreads();
      buf[tid] += t;
      __syncthreads();
    }
    int incl = buf[tid];
    int c = s_carry;
    if (i < NN) {
      ip[i] = c + incl - v;
      dinv[i] = (v > 0) ? rsqrtf((float)v) : 0.f;
    }
    __syncthreads();
    if (tid == 1023) s_carry = c + buf[1023];
    __syncthreads();
  }
  if (tid == 0) ip[NN] = s_carry;
}

__global__ void csr_fill(const int* __restrict__ ei, const float* __restrict__ dinv,
                         const int* __restrict__ ip, int* __restrict__ cur,
                         int* __restrict__ csrs, float* __restrict__ csrn) {
  int e = blockIdx.x*256 + threadIdx.x;
  if (e >= NE) return;
  int s = ei[e], d = ei[NE + e];
  int pos = ip[d] + atomicAdd(&cur[d], 1);
  csrs[pos] = s;
  csrn[pos] = dinv[s]*dinv[d];
}

// ==================== fused CNN encoder (r9 config: 1024 thr, acc[5][2]) ====================
__global__ __launch_bounds__(1024) void cnn_kernel(
    const float* __restrict__ inp, const f16* __restrict__ W1T, const float* __restrict__ b1,
    const f16* __restrict__ W2T, const float* __restrict__ b2,
    const f16* __restrict__ W3T, const float* __restrict__ b3,
    f16* __restrict__ h0)
{
  extern __shared__ char smem[];
  float* s_in = (float*)(smem + L_IN);    // [53][6] f32
  f16*   s_a1 = (f16*)(smem + L_A1);      // [208][40] im2col (k<9 data)
  f16*   s_c1 = (f16*)(smem + L_C1);      // [208][136] row'=y+52x, col=cin
  f16*   s_c2 = (f16*)(smem + L_C2);      // [147][216] row=3*y3+x3, col=cout

  const int node = blockIdx.x;
  const int tid  = threadIdx.x;
  const int lane = tid & 63, wid = tid >> 6;     // wid 0..15
  const int l15 = lane & 15, g = lane >> 4;

  for (int i = tid; i < 318; i += 1024) s_in[i] = inp[node*318 + i];
  __syncthreads();

  // ---- im2col A1[m][k] = in[(y+ky)*6 + x+kx], m=4y+x, k=ky*3+kx ----
  for (int i = tid; i < 208*32; i += 1024) {
    int m = i >> 5, k = i & 31;
    float v = 0.f;
    if (m < 204 && k < 9) {
      int y = m >> 2, x = m & 3;
      int ky = (k >= 6) ? 2 : (k >= 3 ? 1 : 0);
      int kx = k - ky*3;
      v = s_in[(y + ky)*6 + x + kx];
    }
    s_a1[m*40 + k] = (f16)v;
  }
  __syncthreads();

  // ---- conv1 (1->100) SWAPPED MFMA: D[cout][pos]; covers ALL 208x112 of c1 ----
  for (int p = wid; p < 91; p += 16) {
    int mt = p % 13, nt = p / 13;
    f16x8 a = *(const f16x8*)(W1T + (nt*16 + l15)*32 + g*8);   // A row = cout
    f16x8 b = *(const f16x8*)(s_a1 + (mt*16 + l15)*40 + g*8);  // B col = position
    f32x4 acc = (f32x4){0.f,0.f,0.f,0.f};
    acc = __builtin_amdgcn_mfma_f32_16x16x32_f16(a, b, acc, 0, 0, 0);
    int m = mt*16 + l15;                         // position m = 4y+x
    int rowp = (m >> 2) + 52*(m & 3);            // column-major row'
    int cb = nt*16 + g*4;
    f16x4 pack;
    #pragma unroll
    for (int j = 0; j < 4; j++) {
      int c = cb + j;
      float bias = (c < 100) ? b1[c] : 0.f;      // cout>=100: W1T rows zero -> acc 0
      float v = acc[j] + bias;
      v = v > 0.f ? v : 0.01f*v;
      pack[j] = (f16)v;
    }
    *(f16x4*)(s_c1 + rowp*C1_STRIDE + cb) = pack;
  }
  __syncthreads();

  // ---- conv2 (100->200) SWAPPED MFMA GEMM: D[cout][pos] ----
  const int wm = wid >> 3, wn = wid & 7;          // 2x8 wave grid, wave tile 80x32

  const f16* abase[5];
  #pragma unroll
  for (int mi = 0; mi < 5; mi++) {
    int p = (wm*5 + mi)*16 + l15;
    int pp = p < 147 ? p : 0;
    int y2 = pp / 3;
    int x2 = pp - y2*3;
    abase[mi] = s_c1 + (y2 + 52*x2)*C1_STRIDE + g*8;
  }

  f32x4 acc[5][2];
  #pragma unroll
  for (int mi = 0; mi < 5; mi++)
    #pragma unroll
    for (int ni = 0; ni < 2; ni++)
      acc[mi][ni] = (f32x4){0.f,0.f,0.f,0.f};

  const f16* bbase = W2T + wn*1024 + l15*32 + g*8;   // fragment-linear, lane row = cout
  #pragma unroll
  for (int kc = 0; kc < 21; kc++) {
    f16x8 b[2];
    const f16* bkc = bbase + kc*8192;
    #pragma unroll
    for (int ni = 0; ni < 2; ni++)
      b[ni] = *(const f16x8*)(bkc + ni*512);
    int kg0 = kc*32;
    int tap0 = kg0 / 112;
    int rem0 = kg0 - tap0*112;
    int cfull = rem0 + g*8;
    int wrap = cfull >= 112 ? 1 : 0;
    int c = cfull - wrap*112;
    int tapg = tap0 + wrap;                       // tap = ky*2+kx
    int dr = (tapg >> 1) + 52*(tapg & 1);         // row' delta = ky + 52*kx
    int aoff = dr*C1_STRIDE + (c - g*8);          // abase already has +g*8
    #pragma unroll
    for (int mi = 0; mi < 5; mi++) {
      f16x8 a = *(const f16x8*)(abase[mi] + aoff);
      #pragma unroll
      for (int ni = 0; ni < 2; ni++)   // SWAPPED: A-op = weights, B-op = activations
        acc[mi][ni] = __builtin_amdgcn_mfma_f32_16x16x32_f16(b[ni], a, acc[mi][ni], 0, 0, 0);
    }
  }

  __syncthreads();   // all reads of s_c1/s_a1 done before s_c2 overwrites

  // epilogue: D[row=cout][col=pos]; packed b64 stores. GUARD nb<216 (race fix, r6).
  #pragma unroll
  for (int ni = 0; ni < 2; ni++) {
    int nb = wn*32 + ni*16 + g*4;
    if (nb < 216) {
      #pragma unroll
      for (int mi = 0; mi < 5; mi++) {
        int m = (wm*5 + mi)*16 + l15;
        if (m < 147) {
          f16x4 pack;
          #pragma unroll
          for (int j = 0; j < 4; j++) {
            int n = nb + j;
            float bias = (n < 200) ? b2[n] : 0.f;
            float v = acc[mi][ni][j] + bias;
            v = v > 0.f ? v : 0.01f*v;
            pack[j] = (f16)v;
          }
          *(f16x4*)(s_c2 + m*216 + nb) = pack;
        }
      }
    }
  }
  __syncthreads();

  // ---- conv3 (200->1) SWAPPED skinny MFMA + tanh -> h0 ----
  if (wid < 6) {
    int pos = wid*16 + l15;
    int q = pos < 94 ? pos : 0;
    int r3 = (q >> 1)*3 + (q & 1);
    f32x4 acc3 = (f32x4){0.f,0.f,0.f,0.f};
    #pragma unroll
    for (int kc = 0; kc < 39; kc++) {
      int k = kc*32 + g*8;
      int tap = k / 208;
      int c = k - tap*208;
      int dr = (tap >> 1)*3 + (tap & 1);
      f16x8 a = *(const f16x8*)(W3T + k);
      f16x8 b = *(const f16x8*)(s_c2 + (r3 + dr)*216 + c);
      acc3 = __builtin_amdgcn_mfma_f32_16x16x32_f16(a, b, acc3, 0, 0, 0);
    }
    if (g == 0) {
      float v = (pos < 94) ? tanhf(acc3[0] + b3[0]) : 0.f;
      h0[node*96 + pos] = (f16)v;
    }
  }
}

// ==================== generic MFMA GEMM: out = A[M][K] * B[N][K]^T ====================
// CT != null: cols 0..255 -> CT f16 [M][256] (t-part); cols 256..511 -> Croot f32 [M][256]
// CT == null: all cols -> Croot f32 [M][N]
template<int K>
__global__ __launch_bounds__(256, 4) void gemm_kernel(
    const f16* __restrict__ A, const f16* __restrict__ B, float* __restrict__ Croot,
    f16* __restrict__ CT, int M, int N)
{
  constexpr int LK = K + 8;
  __shared__ f16 sA[64*LK];
  __shared__ f16 sB[64*LK];
  const int tid = threadIdx.x;
  const int m0 = blockIdx.x*64, n0 = blockIdx.y*64;
  constexpr int SEGS = K/8;
  for (int i = tid; i < 64*SEGS; i += 256) {
    int row = i / SEGS, seg = i - row*SEGS;
    int gm = m0 + row; if (gm >= M) gm = M - 1;
    *(f16x8*)(sA + row*LK + seg*8) = *(const f16x8*)(A + (size_t)gm*K + seg*8);
    *(f16x8*)(sB + row*LK + seg*8) = *(const f16x8*)(B + (size_t)(n0 + row)*K + seg*8);
  }
  __syncthreads();
  const int lane = tid & 63, wid = tid >> 6;
  const int l15 = lane & 15, g = lane >> 4;
  const int wm = wid >> 1, wn = wid & 1;
  f32x4 acc[2][2];
  #pragma unroll
  for (int mi = 0; mi < 2; mi++)
    #pragma unroll
    for (int ni = 0; ni < 2; ni++)
      acc[mi][ni] = (f32x4){0.f,0.f,0.f,0.f};
  #pragma unroll
  for (int kc = 0; kc < K/32; kc++) {
    f16x8 a[2], b[2];
    #pragma unroll
    for (int mi = 0; mi < 2; mi++)
      a[mi] = *(const f16x8*)(sA + (wm*32 + mi*16 + l15)*LK + kc*32 + g*8);
    #pragma unroll
    for (int ni = 0; ni < 2; ni++)
      b[ni] = *(const f16x8*)(sB + (wn*32 + ni*16 + l15)*LK + kc*32 + g*8);
    #pragma unroll
    for (int mi = 0; mi < 2; mi++)
      #pragma unroll
      for (int ni = 0; ni < 2; ni++)
        acc[mi][ni] = __builtin_amdgcn_mfma_f32_16x16x32_f16(a[mi], b[ni], acc[mi][ni], 0, 0, 0);
  }
  if (CT != nullptr && n0 < 256) {
    #pragma unroll
    for (int mi = 0; mi < 2; mi++)
      #pragma unroll
      for (int ni = 0; ni < 2; ni++)
        #pragma unroll
        for (int j = 0; j < 4; j++) {
          int m = m0 + wm*32 + mi*16 + g*4 + j;
          int n = n0 + wn*32 + ni*16 + l15;
          if (m < M) CT[(size_t)m*256 + n] = (f16)acc[mi][ni][j];
        }
  } else if (CT != nullptr) {
    #pragma unroll
    for (int mi = 0; mi < 2; mi++)
      #pragma unroll
      for (int ni = 0; ni < 2; ni++)
        #pragma unroll
        for (int j = 0; j < 4; j++) {
          int m = m0 + wm*32 + mi*16 + g*4 + j;
          int n = n0 + wn*32 + ni*16 + l15 - 256;
          if (m < M) Croot[(size_t)m*256 + n] = acc[mi][ni][j];
        }
  } else {
    #pragma unroll
    for (int mi = 0; mi < 2; mi++)
      #pragma unroll
      for (int ni = 0; ni < 2; ni++)
        #pragma unroll
        for (int j = 0; j < 4; j++) {
          int m = m0 + wm*32 + mi*16 + g*4 + j;
          int n = n0 + wn*32 + ni*16 + l15;
          if (m < M) Croot[(size_t)m*N + n] = acc[mi][ni][j];
        }
  }
}

// ==================== ARMA combine kernels ====================
// CT row: [t_k0(128)|t_k1(128)] f16; Croot row: [root_k0(128)|root_k1(128)] f32
// 2 dst per block, 2 waves per dst (even/odd edges) -> serial gather chain halved.
__global__ __launch_bounds__(256) void combine128(
    const f16* __restrict__ CT, const float* __restrict__ Croot,
    const int* __restrict__ ip, const int* __restrict__ csrs,
    const float* __restrict__ csrn, const float* __restrict__ bias,
    f16* __restrict__ hout)
{
  __shared__ float red[2][4][64];                // [dst-slot][acc][lane]
  const int wid = threadIdx.x >> 6;
  const int ds  = wid >> 1;                      // dst slot 0/1
  const int sub = wid & 1;                       // even/odd edge subset
  const int d = blockIdx.x*2 + ds;
  const int lane = threadIdx.x & 63;
  const int c = lane*2;
  const int i0 = ip[d], i1 = ip[d+1];
  float a00=0.f, a01=0.f, a10=0.f, a11=0.f;
  float b00=0.f, b01=0.f, b10=0.f, b11=0.f;
  int e = i0 + sub;
  for (; e + 2 < i1; e += 4) {                   // edges e and e+2: 8 streams/wave
    int s0 = csrs[e], s1 = csrs[e+2];
    float w0 = csrn[e], w1 = csrn[e+2];
    f16x2 t00 = *(const f16x2*)(CT + (size_t)s0*256 + c);
    f16x2 t01 = *(const f16x2*)(CT + (size_t)s0*256 + 128 + c);
    f16x2 t10 = *(const f16x2*)(CT + (size_t)s1*256 + c);
    f16x2 t11 = *(const f16x2*)(CT + (size_t)s1*256 + 128 + c);
    a00 += w0*(float)t00.x;  a01 += w0*(float)t00.y;
    a10 += w0*(float)t01.x;  a11 += w0*(float)t01.y;
    b00 += w1*(float)t10.x;  b01 += w1*(float)t10.y;
    b10 += w1*(float)t11.x;  b11 += w1*(float)t11.y;
  }
  if (e < i1) {
    int s = csrs[e];
    float w = csrn[e];
    f16x2 t0 = *(const f16x2*)(CT + (size_t)s*256 + c);
    f16x2 t1 = *(const f16x2*)(CT + (size_t)s*256 + 128 + c);
    a00 += w*(float)t0.x;  a01 += w*(float)t0.y;
    a10 += w*(float)t1.x;  a11 += w*(float)t1.y;
  }
  a00 += b00; a01 += b01; a10 += b10; a11 += b11;
  if (sub == 1) {                                // odd wave -> LDS
    red[ds][0][lane] = a00;  red[ds][1][lane] = a01;
    red[ds][2][lane] = a10;  red[ds][3][lane] = a11;
  }
  __syncthreads();
  if (sub == 0) {
    a00 += red[ds][0][lane];  a01 += red[ds][1][lane];
    a10 += red[ds][2][lane];  a11 += red[ds][3][lane];
    const float* r = Croot + (size_t)d*256;
    float o0 = 0.5f*(fmaxf(a00 + r[c]       + bias[c],       0.f)
                   + fmaxf(a10 + r[128 + c] + bias[128 + c], 0.f));
    float o1 = 0.5f*(fmaxf(a01 + r[c + 1]   + bias[c + 1],   0.f)
                   + fmaxf(a11 + r[129 + c] + bias[129 + c], 0.f));
    f16x2 ov; ov.x = (f16)tanhf(o0); ov.y = (f16)tanhf(o1);
    *(f16x2*)(hout + (size_t)d*128 + c) = ov;
  }
}

// layer 6 (K=1, Fout=16): CR row = [t(16)|root(16)|...]; relu -> softmax -> out
__global__ __launch_bounds__(256) void combine_out(
    const float* __restrict__ C, const int* __restrict__ ip,
    const int* __restrict__ csrs, const float* __restrict__ csrn,
    const float* __restrict__ bias, float* __restrict__ out)
{
  const int d = blockIdx.x*4 + (threadIdx.x >> 6);
  const int lane = threadIdx.x & 63;
  const int f = lane & 15;
  const int i0 = ip[d], i1 = ip[d+1];
  float a = 0.f, b = 0.f;
  int e = i0;
  for (; e + 1 < i1; e += 2) {
    a += csrn[e]   * C[(size_t)csrs[e]*64 + f];
    b += csrn[e+1] * C[(size_t)csrs[e+1]*64 + f];
  }
  if (e < i1) a += csrn[e] * C[(size_t)csrs[e]*64 + f];
  a += b;
  float v = fmaxf(a + C[(size_t)d*64 + 16 + f] + bias[f], 0.f);
  float m = v;
  #pragma unroll
  for (int off = 1; off < 16; off <<= 1) m = fmaxf(m, __shfl_xor(m, off));
  float ev = expf(v - m);
  float s = ev;
  #pragma unroll
  for (int off = 1; off < 16; off <<= 1) s += __shfl_xor(s, off);
  if (lane < 16) out[(size_t)d*16 + lane] = ev / s;
}

// ==================== host ====================
extern "C" void kernel_launch(void* const* d_in, const int* in_sizes, int n_in,
                              void* d_out, int out_size, void* d_ws, size_t ws_size,
                              hipStream_t stream)
{
  const float* inputs = (const float*)d_in[0];
  const int*   ei     = (const int*)d_in[1];
  const float* e1w = (const float*)d_in[2];
  const float* e1b = (const float*)d_in[3];
  const float* e2w = (const float*)d_in[4];
  const float* e2b = (const float*)d_in[5];
  const float* e3w = (const float*)d_in[6];
  const float* e3b = (const float*)d_in[7];
  const float *awi[6], *awr[6], *ab[6];
  for (int i = 0; i < 6; i++) {
    awi[i] = (const float*)d_in[8 + 3*i];
    awr[i] = (const float*)d_in[9 + 3*i];
    ab[i]  = (const float*)d_in[10 + 3*i];
  }
  char* ws = (char*)d_ws;
  f16* W2T = (f16*)(ws + OFF_W2T);
  f16* W3T = (f16*)(ws + OFF_W3T);
  f16* W1T = (f16*)(ws + OFF_W1T);
  f16* WT[6] = { (f16*)(ws + OFF_WT1), (f16*)(ws + OFF_WT2), (f16*)(ws + OFF_WT3),
                 (f16*)(ws + OFF_WT4), (f16*)(ws + OFF_WT5), (f16*)(ws + OFF_WT6) };
  f16* H0 = (f16*)(ws + OFF_H0);
  f16* HA = (f16*)(ws + OFF_HA);
  f16* HB = (f16*)(ws + OFF_HB);
  float* CR = (float*)(ws + OFF_C);
  f16* CT  = (f16*)(ws + OFF_CT);
  int* DEG = (int*)(ws + OFF_DEG);
  int* IP  = (int*)(ws + OFF_IP);
  int* CUR = (int*)(ws + OFF_CUR);
  float* DINV = (float*)(ws + OFF_DINV);
  int* CSRS = (int*)(ws + OFF_CSRS);
  float* CSRN = (float*)(ws + OFF_CSRN);

  (void)hipFuncSetAttribute((const void*)cnn_kernel,
                            hipFuncAttributeMaxDynamicSharedMemorySize, LDS_TOTAL);

  // all weight prep in ONE launch (W1T aliases CR; cnn reads it before gemm writes CR)
  prep_all<<<1939, 256, 0, stream>>>(ws, e1w, e2w, e3w,
                                     awi[0], awr[0], awi[1], awr[1], awi[2], awr[2],
                                     awi[3], awr[3], awi[4], awr[4], awi[5], awr[5]);

  // graph norm + CSR by dst
  (void)hipMemsetAsync(DEG, 0, NN*sizeof(int), stream);
  (void)hipMemsetAsync(CUR, 0, NN*sizeof(int), stream);
  deg_kernel<<<625, 256, 0, stream>>>(ei, DEG);
  scan_kernel<<<1, 1024, 0, stream>>>(DEG, IP, DINV);
  csr_fill<<<625, 256, 0, stream>>>(ei, DINV, IP, CUR, CSRS, CSRN);

  // fused CNN encoder -> h0 f16 [5000][96]
  cnn_kernel<<<NN, 1024, LDS_TOTAL, stream>>>(inputs, W1T, e1b, W2T, e2b, W3T, e3b, H0);

  // ARMA stack
  gemm_kernel<96><<<dim3(79, 8), 256, 0, stream>>>(H0, WT[0], CR, CT, NN, 512);
  combine128<<<2500, 256, 0, stream>>>(CT, CR, IP, CSRS, CSRN, ab[0], HA);
  gemm_kernel<128><<<dim3(79, 8), 256, 0, stream>>>(HA, WT[1], CR, CT, NN, 512);
  combine128<<<2500, 256, 0, stream>>>(CT, CR, IP, CSRS, CSRN, ab[1], HB);
  gemm_kernel<128><<<dim3(79, 8), 256, 0, stream>>>(HB, WT[2], CR, CT, NN, 512);
  combine128<<<2500, 256, 0, stream>>>(CT, CR, IP, CSRS, CSRN, ab[2], HA);
  gemm_kernel<128><<<dim3(79, 8), 256, 0, stream>>>(HA, WT[3], CR, CT, NN, 512);
  combine128<<<2500, 256, 0, stream>>>(CT, CR, IP, CSRS, CSRN, ab[3], HB);
  gemm_kernel<128><<<dim3(79, 8), 256, 0, stream>>>(HB, WT[4], CR, CT, NN, 512);
  combine128<<<2500, 256, 0, stream>>>(CT, CR, IP, CSRS, CSRN, ab[4], HA);
  gemm_kernel<128><<<dim3(79, 1), 256, 0, stream>>>(HA, WT[5], CR, nullptr, NN, 64);
  combine_out<<<1250, 256, 0, stream>>>(CR, IP, CSRS, CSRN, ab[5], (float*)d_out);
}

// Round 12
// 627.606 us; speedup vs baseline: 1.1253x; 1.0424x over previous
//
#include <hip/hip_runtime.h>
#include <math.h>

typedef _Float16 f16;
typedef _Float16 f16x2 __attribute__((ext_vector_type(2)));
typedef _Float16 f16x4 __attribute__((ext_vector_type(4)));
typedef _Float16 f16x8 __attribute__((ext_vector_type(8)));
typedef float f32x4 __attribute__((ext_vector_type(4)));

#define NN 5000
#define NE 160000

// ---------------- ws layout (bytes, all 16B-aligned) ----------------
#define OFF_W2T   0ul          // f16 [21][256][4][8] fragment-linear (344064 B)
#define OFF_W3T   344064ul     // f16 [1248]
#define OFF_WT1   346560ul     // f16 [512][96]
#define OFF_WT2   444864ul     // f16 [512][128]
#define OFF_WT3   575936ul
#define OFF_WT4   707008ul
#define OFF_WT5   838080ul
#define OFF_WT6   969152ul     // f16 [64][128]
#define OFF_H0    985536ul     // f16 [5000][96]
#define OFF_HA    1945536ul    // f16 [5000][128]
#define OFF_HB    3225536ul    // f16 [5000][128]
#define OFF_C     4505536ul    // f32 [5000][256] root (also f32 [5000][64] layer 6)
#define OFF_CT    9625536ul    // f16 [5000][256] t-part (gathered)
#define OFF_DEG   14745536ul   // int [5000]
#define OFF_IP    14765536ul   // int [5001]
#define OFF_CUR   14785568ul   // int [5000]
#define OFF_DINV  14805568ul   // f32 [5000]
#define OFF_CSRS  14825568ul   // int [160000]
#define OFF_CSRN  15465568ul   // f32 [160000]
// W1T f16 [112][32] aliases OFF_C (dead before first gemm writes CR)
#define OFF_W1T   OFF_C
// scan scratch aliases CT (CT first written by gemm1, after scan done)
#define OFF_BSUM  OFF_CT            // int [21]
#define OFF_PART  (OFF_CT + 128ul)  // int [5000]

// ---------------- CNN LDS layout (dynamic, 74496 B) ----------------
#define L_IN   0
#define L_BUF  1280
#define L_A1   (L_BUF)
#define L_C1   (L_BUF + 16640)            // 17920
#define L_C2   (L_BUF)
#define C1_STRIDE 136                     // f16 elems (272 B/row)
#define LDS_TOTAL (17920 + 208*272)       // 74496

// ==================== fused weight-prep ====================
__device__ __forceinline__ void wt_body(int i, const float* wi, const float* wr,
                                        f16* WT, int Kst, int Fin, int Fout, int Kpad) {
  int n = i / Kpad, kk = i - n*Kpad;
  float v = 0.f;
  if (kk < Fin) {
    int path = n / (Kst*Fout);
    if (path < 2) {
      int rem = n - path*(Kst*Fout);
      int k = rem / Fout, fo = rem - k*Fout;
      const float* w = (path == 0) ? wi : wr;
      v = w[(k*Fin + kk)*Fout + fo];
    }
  }
  WT[i] = (f16)v;
}

// grid: [0,672) W2T | [672,677) W3T | [677,691) W1T | [691,883) WT1 |
// [883,1139) WT2 | [1139,1395) WT3 | [1395,1651) WT4 | [1651,1907) WT5 | [1907,1939) WT6
__global__ void prep_all(char* ws, const float* __restrict__ e1w,
                         const float* __restrict__ e2w, const float* __restrict__ e3w,
                         const float* wi1, const float* wr1, const float* wi2, const float* wr2,
                         const float* wi3, const float* wr3, const float* wi4, const float* wr4,
                         const float* wi5, const float* wr5, const float* wi6, const float* wr6) {
  int b = blockIdx.x, tid = threadIdx.x;
  if (b < 672) {                                  // W2T fragment-linear
    int i = b*256 + tid;
    int kc = i >> 13, n = (i >> 5) & 255;
    int k = i & 31;                               // k offset within kc (= g*8+j)
    int kk = kc*32 + k;
    int tap = kk / 112, c = kk - tap*112;
    float v = 0.f;
    if (n < 200 && c < 100 && tap < 6) v = e2w[n*600 + c*6 + tap];
    ((f16*)(ws + OFF_W2T))[i] = (f16)v;
  } else if (b < 677) {                           // W3T
    int i = (b - 672)*256 + tid;
    if (i < 1248) {
      int tap = i / 208, c = i - tap*208;
      float v = (c < 200) ? e3w[c*6 + tap] : 0.f;
      ((f16*)(ws + OFF_W3T))[i] = (f16)v;
    }
  } else if (b < 691) {                           // W1T
    int i = (b - 677)*256 + tid;
    if (i < 112*32) {
      int n = i >> 5, k = i & 31;
      float v = (n < 100 && k < 9) ? e1w[n*9 + k] : 0.f;
      ((f16*)(ws + OFF_W1T))[i] = (f16)v;
    }
  } else if (b < 883) {
    wt_body((b - 691)*256 + tid, wi1, wr1, (f16*)(ws + OFF_WT1), 2, 94, 128, 96);
  } else if (b < 1139) {
    wt_body((b - 883)*256 + tid, wi2, wr2, (f16*)(ws + OFF_WT2), 2, 128, 128, 128);
  } else if (b < 1395) {
    wt_body((b - 1139)*256 + tid, wi3, wr3, (f16*)(ws + OFF_WT3), 2, 128, 128, 128);
  } else if (b < 1651) {
    wt_body((b - 1395)*256 + tid, wi4, wr4, (f16*)(ws + OFF_WT4), 2, 128, 128, 128);
  } else if (b < 1907) {
    wt_body((b - 1651)*256 + tid, wi5, wr5, (f16*)(ws + OFF_WT5), 2, 128, 128, 128);
  } else {
    wt_body((b - 1907)*256 + tid, wi6, wr6, (f16*)(ws + OFF_WT6), 1, 128, 16, 128);
  }
}

// ==================== graph kernels ====================
__global__ void deg_kernel(const int* __restrict__ ei, int* __restrict__ deg) {
  int e = blockIdx.x*256 + threadIdx.x;
  if (e < NE) atomicAdd(&deg[ei[NE + e]], 1);
}

// multi-block scan: scan1 (per-block) -> scan2 (block sums) -> scan3 (add offsets)
__global__ void scan1(const int* __restrict__ deg, int* __restrict__ part,
                      int* __restrict__ bsum, float* __restrict__ dinv) {
  __shared__ int buf[256];
  const int tid = threadIdx.x;
  const int i = blockIdx.x*256 + tid;
  int v = (i < NN) ? deg[i] : 0;
  buf[tid] = v;
  __syncthreads();
  #pragma unroll
  for (int off = 1; off < 256; off <<= 1) {
    int t = (tid >= off) ? buf[tid - off] : 0;
    __syncthreads();
    buf[tid] += t;
    __syncthreads();
  }
  if (i < NN) {
    part[i] = buf[tid] - v;                       // exclusive within block
    dinv[i] = (v > 0) ? rsqrtf((float)v) : 0.f;
  }
  if (tid == 255) bsum[blockIdx.x] = buf[255];
}

__global__ void scan2(int* __restrict__ bsum) {
  if (threadIdx.x == 0) {
    int acc = 0;
    #pragma unroll
    for (int b = 0; b < 20; b++) { int t = bsum[b]; bsum[b] = acc; acc += t; }
    bsum[20] = acc;
  }
}

__global__ void scan3(const int* __restrict__ part, const int* __restrict__ bsum,
                      int* __restrict__ ip) {
  int i = blockIdx.x*256 + threadIdx.x;
  if (i < NN) ip[i] = part[i] + bsum[blockIdx.x];
  if (i == 0) ip[NN] = bsum[20];
}

__global__ void csr_fill(const int* __restrict__ ei, const float* __restrict__ dinv,
                         const int* __restrict__ ip, int* __restrict__ cur,
                         int* __restrict__ csrs, float* __restrict__ csrn) {
  int e = blockIdx.x*256 + threadIdx.x;
  if (e >= NE) return;
  int s = ei[e], d = ei[NE + e];
  int pos = ip[d] + atomicAdd(&cur[d], 1);
  csrs[pos] = s;
  csrn[pos] = dinv[s]*dinv[d];
}

// ==================== fused CNN encoder (frozen r9 config: 1024 thr, acc[5][2]) ====================
__global__ __launch_bounds__(1024) void cnn_kernel(
    const float* __restrict__ inp, const f16* __restrict__ W1T, const float* __restrict__ b1,
    const f16* __restrict__ W2T, const float* __restrict__ b2,
    const f16* __restrict__ W3T, const float* __restrict__ b3,
    f16* __restrict__ h0)
{
  extern __shared__ char smem[];
  float* s_in = (float*)(smem + L_IN);    // [53][6] f32
  f16*   s_a1 = (f16*)(smem + L_A1);      // [208][40] im2col (k<9 data)
  f16*   s_c1 = (f16*)(smem + L_C1);      // [208][136] row'=y+52x, col=cin
  f16*   s_c2 = (f16*)(smem + L_C2);      // [147][216] row=3*y3+x3, col=cout

  const int node = blockIdx.x;
  const int tid  = threadIdx.x;
  const int lane = tid & 63, wid = tid >> 6;     // wid 0..15
  const int l15 = lane & 15, g = lane >> 4;

  for (int i = tid; i < 318; i += 1024) s_in[i] = inp[node*318 + i];
  __syncthreads();

  // ---- im2col A1[m][k] = in[(y+ky)*6 + x+kx], m=4y+x, k=ky*3+kx ----
  for (int i = tid; i < 208*32; i += 1024) {
    int m = i >> 5, k = i & 31;
    float v = 0.f;
    if (m < 204 && k < 9) {
      int y = m >> 2, x = m & 3;
      int ky = (k >= 6) ? 2 : (k >= 3 ? 1 : 0);
      int kx = k - ky*3;
      v = s_in[(y + ky)*6 + x + kx];
    }
    s_a1[m*40 + k] = (f16)v;
  }
  __syncthreads();

  // ---- conv1 (1->100) SWAPPED MFMA: D[cout][pos]; covers ALL 208x112 of c1 ----
  for (int p = wid; p < 91; p += 16) {
    int mt = p % 13, nt = p / 13;
    f16x8 a = *(const f16x8*)(W1T + (nt*16 + l15)*32 + g*8);   // A row = cout
    f16x8 b = *(const f16x8*)(s_a1 + (mt*16 + l15)*40 + g*8);  // B col = position
    f32x4 acc = (f32x4){0.f,0.f,0.f,0.f};
    acc = __builtin_amdgcn_mfma_f32_16x16x32_f16(a, b, acc, 0, 0, 0);
    int m = mt*16 + l15;                         // position m = 4y+x
    int rowp = (m >> 2) + 52*(m & 3);            // column-major row'
    int cb = nt*16 + g*4;
    f16x4 pack;
    #pragma unroll
    for (int j = 0; j < 4; j++) {
      int c = cb + j;
      float bias = (c < 100) ? b1[c] : 0.f;      // cout>=100: W1T rows zero -> acc 0
      float v = acc[j] + bias;
      v = v > 0.f ? v : 0.01f*v;
      pack[j] = (f16)v;
    }
    *(f16x4*)(s_c1 + rowp*C1_STRIDE + cb) = pack;
  }
  __syncthreads();

  // ---- conv2 (100->200) SWAPPED MFMA GEMM: D[cout][pos] ----
  const int wm = wid >> 3, wn = wid & 7;          // 2x8 wave grid, wave tile 80x32

  const f16* abase[5];
  #pragma unroll
  for (int mi = 0; mi < 5; mi++) {
    int p = (wm*5 + mi)*16 + l15;
    int pp = p < 147 ? p : 0;
    int y2 = pp / 3;
    int x2 = pp - y2*3;
    abase[mi] = s_c1 + (y2 + 52*x2)*C1_STRIDE + g*8;
  }

  f32x4 acc[5][2];
  #pragma unroll
  for (int mi = 0; mi < 5; mi++)
    #pragma unroll
    for (int ni = 0; ni < 2; ni++)
      acc[mi][ni] = (f32x4){0.f,0.f,0.f,0.f};

  const f16* bbase = W2T + wn*1024 + l15*32 + g*8;   // fragment-linear, lane row = cout
  #pragma unroll
  for (int kc = 0; kc < 21; kc++) {
    f16x8 b[2];
    const f16* bkc = bbase + kc*8192;
    #pragma unroll
    for (int ni = 0; ni < 2; ni++)
      b[ni] = *(const f16x8*)(bkc + ni*512);
    int kg0 = kc*32;
    int tap0 = kg0 / 112;
    int rem0 = kg0 - tap0*112;
    int cfull = rem0 + g*8;
    int wrap = cfull >= 112 ? 1 : 0;
    int c = cfull - wrap*112;
    int tapg = tap0 + wrap;                       // tap = ky*2+kx
    int dr = (tapg >> 1) + 52*(tapg & 1);         // row' delta = ky + 52*kx
    int aoff = dr*C1_STRIDE + (c - g*8);          // abase already has +g*8
    #pragma unroll
    for (int mi = 0; mi < 5; mi++) {
      f16x8 a = *(const f16x8*)(abase[mi] + aoff);
      #pragma unroll
      for (int ni = 0; ni < 2; ni++)   // SWAPPED: A-op = weights, B-op = activations
        acc[mi][ni] = __builtin_amdgcn_mfma_f32_16x16x32_f16(b[ni], a, acc[mi][ni], 0, 0, 0);
    }
  }

  __syncthreads();   // all reads of s_c1/s_a1 done before s_c2 overwrites

  // epilogue: D[row=cout][col=pos]; packed b64 stores. GUARD nb<216 (race fix, r6).
  #pragma unroll
  for (int ni = 0; ni < 2; ni++) {
    int nb = wn*32 + ni*16 + g*4;
    if (nb < 216) {
      #pragma unroll
      for (int mi = 0; mi < 5; mi++) {
        int m = (wm*5 + mi)*16 + l15;
        if (m < 147) {
          f16x4 pack;
          #pragma unroll
          for (int j = 0; j < 4; j++) {
            int n = nb + j;
            float bias = (n < 200) ? b2[n] : 0.f;
            float v = acc[mi][ni][j] + bias;
            v = v > 0.f ? v : 0.01f*v;
            pack[j] = (f16)v;
          }
          *(f16x4*)(s_c2 + m*216 + nb) = pack;
        }
      }
    }
  }
  __syncthreads();

  // ---- conv3 (200->1) SWAPPED skinny MFMA + tanh -> h0 ----
  if (wid < 6) {
    int pos = wid*16 + l15;
    int q = pos < 94 ? pos : 0;
    int r3 = (q >> 1)*3 + (q & 1);
    f32x4 acc3 = (f32x4){0.f,0.f,0.f,0.f};
    #pragma unroll
    for (int kc = 0; kc < 39; kc++) {
      int k = kc*32 + g*8;
      int tap = k / 208;
      int c = k - tap*208;
      int dr = (tap >> 1)*3 + (tap & 1);
      f16x8 a = *(const f16x8*)(W3T + k);
      f16x8 b = *(const f16x8*)(s_c2 + (r3 + dr)*216 + c);
      acc3 = __builtin_amdgcn_mfma_f32_16x16x32_f16(a, b, acc3, 0, 0, 0);
    }
    if (g == 0) {
      float v = (pos < 94) ? tanhf(acc3[0] + b3[0]) : 0.f;
      h0[node*96 + pos] = (f16)v;
    }
  }
}

// ==================== generic MFMA GEMM: out = A[M][K] * B[N][K]^T ====================
// CT != null: cols 0..255 -> CT f16 [M][256] (t-part); cols 256..511 -> Croot f32 [M][256]
// CT == null: all cols -> Croot f32 [M][N]
template<int K>
__global__ __launch_bounds__(256, 4) void gemm_kernel(
    const f16* __restrict__ A, const f16* __restrict__ B, float* __restrict__ Croot,
    f16* __restrict__ CT, int M, int N)
{
  constexpr int LK = K + 8;
  __shared__ f16 sA[64*LK];
  __shared__ f16 sB[64*LK];
  const int tid = threadIdx.x;
  const int m0 = blockIdx.x*64, n0 = blockIdx.y*64;
  constexpr int SEGS = K/8;
  for (int i = tid; i < 64*SEGS; i += 256) {
    int row = i / SEGS, seg = i - row*SEGS;
    int gm = m0 + row; if (gm >= M) gm = M - 1;
    *(f16x8*)(sA + row*LK + seg*8) = *(const f16x8*)(A + (size_t)gm*K + seg*8);
    *(f16x8*)(sB + row*LK + seg*8) = *(const f16x8*)(B + (size_t)(n0 + row)*K + seg*8);
  }
  __syncthreads();
  const int lane = tid & 63, wid = tid >> 6;
  const int l15 = lane & 15, g = lane >> 4;
  const int wm = wid >> 1, wn = wid & 1;
  f32x4 acc[2][2];
  #pragma unroll
  for (int mi = 0; mi < 2; mi++)
    #pragma unroll
    for (int ni = 0; ni < 2; ni++)
      acc[mi][ni] = (f32x4){0.f,0.f,0.f,0.f};
  #pragma unroll
  for (int kc = 0; kc < K/32; kc++) {
    f16x8 a[2], b[2];
    #pragma unroll
    for (int mi = 0; mi < 2; mi++)
      a[mi] = *(const f16x8*)(sA + (wm*32 + mi*16 + l15)*LK + kc*32 + g*8);
    #pragma unroll
    for (int ni = 0; ni < 2; ni++)
      b[ni] = *(const f16x8*)(sB + (wn*32 + ni*16 + l15)*LK + kc*32 + g*8);
    #pragma unroll
    for (int mi = 0; mi < 2; mi++)
      #pragma unroll
      for (int ni = 0; ni < 2; ni++)
        acc[mi][ni] = __builtin_amdgcn_mfma_f32_16x16x32_f16(a[mi], b[ni], acc[mi][ni], 0, 0, 0);
  }
  if (CT != nullptr && n0 < 256) {
    #pragma unroll
    for (int mi = 0; mi < 2; mi++)
      #pragma unroll
      for (int ni = 0; ni < 2; ni++)
        #pragma unroll
        for (int j = 0; j < 4; j++) {
          int m = m0 + wm*32 + mi*16 + g*4 + j;
          int n = n0 + wn*32 + ni*16 + l15;
          if (m < M) CT[(size_t)m*256 + n] = (f16)acc[mi][ni][j];
        }
  } else if (CT != nullptr) {
    #pragma unroll
    for (int mi = 0; mi < 2; mi++)
      #pragma unroll
      for (int ni = 0; ni < 2; ni++)
        #pragma unroll
        for (int j = 0; j < 4; j++) {
          int m = m0 + wm*32 + mi*16 + g*4 + j;
          int n = n0 + wn*32 + ni*16 + l15 - 256;
          if (m < M) Croot[(size_t)m*256 + n] = acc[mi][ni][j];
        }
  } else {
    #pragma unroll
    for (int mi = 0; mi < 2; mi++)
      #pragma unroll
      for (int ni = 0; ni < 2; ni++)
        #pragma unroll
        for (int j = 0; j < 4; j++) {
          int m = m0 + wm*32 + mi*16 + g*4 + j;
          int n = n0 + wn*32 + ni*16 + l15;
          if (m < M) Croot[(size_t)m*N + n] = acc[mi][ni][j];
        }
  }
}

// ==================== ARMA combine kernels ====================
// CT row: [t_k0(128)|t_k1(128)] f16; Croot row: [root_k0(128)|root_k1(128)] f32
// 2 dst per block, 2 waves per dst (even/odd), 4-edge unroll -> 16 loads in flight.
__global__ __launch_bounds__(256) void combine128(
    const f16* __restrict__ CT, const float* __restrict__ Croot,
    const int* __restrict__ ip, const int* __restrict__ csrs,
    const float* __restrict__ csrn, const float* __restrict__ bias,
    f16* __restrict__ hout)
{
  __shared__ float red[2][4][64];                // [dst-slot][acc][lane]
  const int wid = threadIdx.x >> 6;
  const int ds  = wid >> 1;                      // dst slot 0/1
  const int sub = wid & 1;                       // even/odd edge subset
  const int d = blockIdx.x*2 + ds;
  const int lane = threadIdx.x & 63;
  const int c = lane*2;
  const int i0 = ip[d], i1 = ip[d+1];
  float a00=0.f, a01=0.f, a10=0.f, a11=0.f;
  float b00=0.f, b01=0.f, b10=0.f, b11=0.f;
  float c00=0.f, c01=0.f, c10=0.f, c11=0.f;
  float d00=0.f, d01=0.f, d10=0.f, d11=0.f;
  int e = i0 + sub;
  for (; e + 6 < i1; e += 8) {                   // 4 edges/iter: 16 streams/wave
    int s0 = csrs[e], s1 = csrs[e+2], s2 = csrs[e+4], s3 = csrs[e+6];
    float w0 = csrn[e], w1 = csrn[e+2], w2 = csrn[e+4], w3 = csrn[e+6];
    f16x2 t00 = *(const f16x2*)(CT + (size_t)s0*256 + c);
    f16x2 t01 = *(const f16x2*)(CT + (size_t)s0*256 + 128 + c);
    f16x2 t10 = *(const f16x2*)(CT + (size_t)s1*256 + c);
    f16x2 t11 = *(const f16x2*)(CT + (size_t)s1*256 + 128 + c);
    f16x2 t20 = *(const f16x2*)(CT + (size_t)s2*256 + c);
    f16x2 t21 = *(const f16x2*)(CT + (size_t)s2*256 + 128 + c);
    f16x2 t30 = *(const f16x2*)(CT + (size_t)s3*256 + c);
    f16x2 t31 = *(const f16x2*)(CT + (size_t)s3*256 + 128 + c);
    a00 += w0*(float)t00.x;  a01 += w0*(float)t00.y;
    a10 += w0*(float)t01.x;  a11 += w0*(float)t01.y;
    b00 += w1*(float)t10.x;  b01 += w1*(float)t10.y;
    b10 += w1*(float)t11.x;  b11 += w1*(float)t11.y;
    c00 += w2*(float)t20.x;  c01 += w2*(float)t20.y;
    c10 += w2*(float)t21.x;  c11 += w2*(float)t21.y;
    d00 += w3*(float)t30.x;  d01 += w3*(float)t30.y;
    d10 += w3*(float)t31.x;  d11 += w3*(float)t31.y;
  }
  for (; e < i1; e += 2) {
    int s = csrs[e];
    float w = csrn[e];
    f16x2 t0 = *(const f16x2*)(CT + (size_t)s*256 + c);
    f16x2 t1 = *(const f16x2*)(CT + (size_t)s*256 + 128 + c);
    a00 += w*(float)t0.x;  a01 += w*(float)t0.y;
    a10 += w*(float)t1.x;  a11 += w*(float)t1.y;
  }
  a00 += b00 + c00 + d00;  a01 += b01 + c01 + d01;
  a10 += b10 + c10 + d10;  a11 += b11 + c11 + d11;
  if (sub == 1) {                                // odd wave -> LDS
    red[ds][0][lane] = a00;  red[ds][1][lane] = a01;
    red[ds][2][lane] = a10;  red[ds][3][lane] = a11;
  }
  __syncthreads();
  if (sub == 0) {
    a00 += red[ds][0][lane];  a01 += red[ds][1][lane];
    a10 += red[ds][2][lane];  a11 += red[ds][3][lane];
    const float* r = Croot + (size_t)d*256;
    float o0 = 0.5f*(fmaxf(a00 + r[c]       + bias[c],       0.f)
                   + fmaxf(a10 + r[128 + c] + bias[128 + c], 0.f));
    float o1 = 0.5f*(fmaxf(a01 + r[c + 1]   + bias[c + 1],   0.f)
                   + fmaxf(a11 + r[129 + c] + bias[129 + c], 0.f));
    f16x2 ov; ov.x = (f16)tanhf(o0); ov.y = (f16)tanhf(o1);
    *(f16x2*)(hout + (size_t)d*128 + c) = ov;
  }
}

// layer 6 (K=1, Fout=16): CR row = [t(16)|root(16)|...]; relu -> softmax -> out.
// Edges split over the 4 16-lane groups (+2-unroll) -> 8x MLP; shfl-reduce groups.
__global__ __launch_bounds__(256) void combine_out(
    const float* __restrict__ C, const int* __restrict__ ip,
    const int* __restrict__ csrs, const float* __restrict__ csrn,
    const float* __restrict__ bias, float* __restrict__ out)
{
  const int d = blockIdx.x*4 + (threadIdx.x >> 6);
  const int lane = threadIdx.x & 63;
  const int f = lane & 15;
  const int grp = lane >> 4;                     // 0..3
  const int i0 = ip[d], i1 = ip[d+1];
  float a = 0.f, b = 0.f;
  int e = i0 + grp;
  for (; e + 4 < i1; e += 8) {
    a += csrn[e]   * C[(size_t)csrs[e]*64 + f];
    b += csrn[e+4] * C[(size_t)csrs[e+4]*64 + f];
  }
  if (e < i1) a += csrn[e] * C[(size_t)csrs[e]*64 + f];
  a += b;
  a += __shfl_xor(a, 16);                        // reduce over the 4 groups
  a += __shfl_xor(a, 32);
  float v = fmaxf(a + C[(size_t)d*64 + 16 + f] + bias[f], 0.f);
  float m = v;
  #pragma unroll
  for (int off = 1; off < 16; off <<= 1) m = fmaxf(m, __shfl_xor(m, off));
  float ev = expf(v - m);
  float s = ev;
  #pragma unroll
  for (int off = 1; off < 16; off <<= 1) s += __shfl_xor(s, off);
  if (lane < 16) out[(size_t)d*16 + lane] = ev / s;
}

// ==================== host ====================
extern "C" void kernel_launch(void* const* d_in, const int* in_sizes, int n_in,
                              void* d_out, int out_size, void* d_ws, size_t ws_size,
                              hipStream_t stream)
{
  const float* inputs = (const float*)d_in[0];
  const int*   ei     = (const int*)d_in[1];
  const float* e1w = (const float*)d_in[2];
  const float* e1b = (const float*)d_in[3];
  const float* e2w = (const float*)d_in[4];
  const float* e2b = (const float*)d_in[5];
  const float* e3w = (const float*)d_in[6];
  const float* e3b = (const float*)d_in[7];
  const float *awi[6], *awr[6], *ab[6];
  for (int i = 0; i < 6; i++) {
    awi[i] = (const float*)d_in[8 + 3*i];
    awr[i] = (const float*)d_in[9 + 3*i];
    ab[i]  = (const float*)d_in[10 + 3*i];
  }
  char* ws = (char*)d_ws;
  f16* W2T = (f16*)(ws + OFF_W2T);
  f16* W3T = (f16*)(ws + OFF_W3T);
  f16* W1T = (f16*)(ws + OFF_W1T);
  f16* WT[6] = { (f16*)(ws + OFF_WT1), (f16*)(ws + OFF_WT2), (f16*)(ws + OFF_WT3),
                 (f16*)(ws + OFF_WT4), (f16*)(ws + OFF_WT5), (f16*)(ws + OFF_WT6) };
  f16* H0 = (f16*)(ws + OFF_H0);
  f16* HA = (f16*)(ws + OFF_HA);
  f16* HB = (f16*)(ws + OFF_HB);
  float* CR = (float*)(ws + OFF_C);
  f16* CT  = (f16*)(ws + OFF_CT);
  int* DEG = (int*)(ws + OFF_DEG);
  int* IP  = (int*)(ws + OFF_IP);
  int* CUR = (int*)(ws + OFF_CUR);
  float* DINV = (float*)(ws + OFF_DINV);
  int* CSRS = (int*)(ws + OFF_CSRS);
  float* CSRN = (float*)(ws + OFF_CSRN);
  int* BSUM = (int*)(ws + OFF_BSUM);
  int* PART = (int*)(ws + OFF_PART);

  (void)hipFuncSetAttribute((const void*)cnn_kernel,
                            hipFuncAttributeMaxDynamicSharedMemorySize, LDS_TOTAL);

  // all weight prep in ONE launch (W1T aliases CR; cnn reads it before gemm writes CR)
  prep_all<<<1939, 256, 0, stream>>>(ws, e1w, e2w, e3w,
                                     awi[0], awr[0], awi[1], awr[1], awi[2], awr[2],
                                     awi[3], awr[3], awi[4], awr[4], awi[5], awr[5]);

  // graph norm + CSR by dst (multi-block scan; PART/BSUM alias CT, dead until gemm1)
  (void)hipMemsetAsync(DEG, 0, NN*sizeof(int), stream);
  (void)hipMemsetAsync(CUR, 0, NN*sizeof(int), stream);
  deg_kernel<<<625, 256, 0, stream>>>(ei, DEG);
  scan1<<<20, 256, 0, stream>>>(DEG, PART, BSUM, DINV);
  scan2<<<1, 64, 0, stream>>>(BSUM);
  scan3<<<20, 256, 0, stream>>>(PART, BSUM, IP);
  csr_fill<<<625, 256, 0, stream>>>(ei, DINV, IP, CUR, CSRS, CSRN);

  // fused CNN encoder -> h0 f16 [5000][96]
  cnn_kernel<<<NN, 1024, LDS_TOTAL, stream>>>(inputs, W1T, e1b, W2T, e2b, W3T, e3b, H0);

  // ARMA stack
  gemm_kernel<96><<<dim3(79, 8), 256, 0, stream>>>(H0, WT[0], CR, CT, NN, 512);
  combine128<<<2500, 256, 0, stream>>>(CT, CR, IP, CSRS, CSRN, ab[0], HA);
  gemm_kernel<128><<<dim3(79, 8), 256, 0, stream>>>(HA, WT[1], CR, CT, NN, 512);
  combine128<<<2500, 256, 0, stream>>>(CT, CR, IP, CSRS, CSRN, ab[1], HB);
  gemm_kernel<128><<<dim3(79, 8), 256, 0, stream>>>(HB, WT[2], CR, CT, NN, 512);
  combine128<<<2500, 256, 0, stream>>>(CT, CR, IP, CSRS, CSRN, ab[2], HA);
  gemm_kernel<128><<<dim3(79, 8), 256, 0, stream>>>(HA, WT[3], CR, CT, NN, 512);
  combine128<<<2500, 256, 0, stream>>>(CT, CR, IP, CSRS, CSRN, ab[3], HB);
  gemm_kernel<128><<<dim3(79, 8), 256, 0, stream>>>(HB, WT[4], CR, CT, NN, 512);
  combine128<<<2500, 256, 0, stream>>>(CT, CR, IP, CSRS, CSRN, ab[4], HA);
  gemm_kernel<128><<<dim3(79, 1), 256, 0, stream>>>(HA, WT[5], CR, nullptr, NN, 64);
  combine_out<<<1250, 256, 0, stream>>>(CR, IP, CSRS, CSRN, ab[5], (float*)d_out);
}